// Round 11
// baseline (192.385 us; speedup 1.0000x reference)
//
#include <hip/hip_runtime.h>

// CentroidPool: argmin_k ||x_i - c_k||^2, N=131072, K=1024, D=128, fp32.
// = argmin_k (0.5||c_k||^2 - x.c_k).
// Pass A: MFMA bf16 hi/lo 3-term split, K-split x2, 128 rows/block,
// 32 rows/wave (nacc=1). r10 lesson: occupancy steps on UNIFIED VGPR+AGPR
// (108+32=140 > 128-step -> 2 waves/SIMD, 19.5% occ, MfmaUtil 41%).
// nacc=1 drops 80 regs -> ~115 unified <= 128 -> __launch_bounds__(256,4)
// = 4 waves/SIMD without spill (r9 spilled because 160+ live > 128 cap).
// Merge kernel combines k-halves; pass B exact fp32 recompute (coalesced).

constexpr int N = 131072;
constexpr int K = 1024;
constexpr int D = 128;
constexpr float EPS2 = 0.05f; // certify margin >> worst-case approx err (~1e-3)

typedef __attribute__((ext_vector_type(8))) short short8;
typedef __attribute__((ext_vector_type(16))) float f32x16;

union U8 { uint4 u; short8 s; };
__device__ inline short8 as_s8(uint4 v) { U8 x; x.u = v; return x.s; }

__device__ inline uint bf16rne(float f) {
    uint u = __float_as_uint(f);
    return (u + 0x7fffu + ((u >> 16) & 1u)) >> 16;
}
__device__ inline void split2(float a, float b, uint& hi, uint& lo) {
    uint ha = bf16rne(a), hb = bf16rne(b);
    float la = a - __uint_as_float(ha << 16);
    float lb = b - __uint_as_float(hb << 16);
    hi = ha | (hb << 16);
    lo = bf16rne(la) | (bf16rne(lb) << 16);
}

// ---- precompute: 0.5*||c_k||^2; block 0 also zeroes the worklist counter ----
__global__ void centroid_c2_kernel(const float* __restrict__ coords,
                                   float* __restrict__ c2half,
                                   int* __restrict__ counter) {
    if (blockIdx.x == 0 && threadIdx.x == 0) counter[0] = 0;
    int k = blockIdx.x * 256 + threadIdx.x;
    if (k >= K) return;
    const float4* row = reinterpret_cast<const float4*>(coords + k * D);
    float s = 0.f;
#pragma unroll
    for (int i = 0; i < D / 4; ++i) {
        float4 v = row[i];
        s += v.x * v.x + v.y * v.y + v.z * v.z + v.w * v.w;
    }
    c2half[k] = 0.5f * s;
}

// ---- precompute: coords -> bf16 hi/lo, row-major [K][64] dwords ----
__global__ void split_kernel(const float* __restrict__ coords,
                             uint* __restrict__ chi, uint* __restrict__ clo) {
    int g = blockIdx.x * 256 + threadIdx.x;
    float a = coords[2 * g], b = coords[2 * g + 1];
    uint hi, lo;
    split2(a, b, hi, lo);
    chi[g] = hi;
    clo[g] = lo;
}

// ---- precompute: coordsT[d][k] = coords[k][d] (LDS-tiled, coalesced) ----
__global__ __launch_bounds__(256) void transpose_kernel(
    const float* __restrict__ coords, float* __restrict__ coordsT) {
    __shared__ float tile[64][65];
    const int k0 = blockIdx.x * 64;
    const int d0 = blockIdx.y * 64;
    const int tx = threadIdx.x & 63, ty = threadIdx.x >> 6;
#pragma unroll
    for (int i = 0; i < 64; i += 4)
        tile[ty + i][tx] = coords[(size_t)(k0 + ty + i) * D + d0 + tx];
    __syncthreads();
#pragma unroll
    for (int i = 0; i < 64; i += 4)
        coordsT[(size_t)(d0 + ty + i) * K + k0 + tx] = tile[tx][ty + i];
}

__device__ inline void stage_load(int kt, int tid, const uint* chi,
                                  const uint* clo, uint4& s0, uint4& s1,
                                  uint4& s2, uint4& s3) {
    const int m = tid & 31, gq = tid >> 5;
    const uint* r = chi + (size_t)(kt * 32 + m) * 64;
    s0 = *(const uint4*)(r + gq * 4);
    s1 = *(const uint4*)(r + (gq + 8) * 4);
    const uint* r2 = clo + (size_t)(kt * 32 + m) * 64;
    s2 = *(const uint4*)(r2 + gq * 4);
    s3 = *(const uint4*)(r2 + (gq + 8) * 4);
}
__device__ inline void stage_write(int buf, int tid, const uint4& s0,
                                   const uint4& s1, const uint4& s2,
                                   const uint4& s3, char* smem) {
    const int m = tid & 31, gq = tid >> 5;
    char* hb = smem + buf * 16384;
    *(uint4*)(hb + m * 256 + ((gq ^ (m & 15)) << 4)) = s0;
    *(uint4*)(hb + m * 256 + (((gq + 8) ^ (m & 15)) << 4)) = s1;
    char* lb = hb + 8192;
    *(uint4*)(lb + m * 256 + ((gq ^ (m & 15)) << 4)) = s2;
    *(uint4*)(lb + m * 256 + (((gq + 8) ^ (m & 15)) << 4)) = s3;
}

__device__ inline void load_row(const float* rp, int h, uint4* bh, uint4* bl) {
#pragma unroll
    for (int c = 0; c < 8; ++c) {
        const float* p = rp + 16 * c + 8 * h;
        float4 u = *(const float4*)(p);
        float4 v = *(const float4*)(p + 4);
        uint h0, l0, h1, l1, h2, l2, h3, l3;
        split2(-u.x, -u.y, h0, l0);
        split2(-u.z, -u.w, h1, l1);
        split2(-v.x, -v.y, h2, l2);
        split2(-v.z, -v.w, h3, l3);
        bh[c] = make_uint4(h0, h1, h2, h3);
        bl[c] = make_uint4(l0, l1, l2, l3);
    }
}

// ---- pass A: MFMA approx over a K-half, 32 rows/wave, (m1,i1,m2) partials ----
__global__ __launch_bounds__(256, 4) void centroid_mfma_partial(
    const float* __restrict__ latent, const uint* __restrict__ chi,
    const uint* __restrict__ clo, const float* __restrict__ c2,
    float* __restrict__ pm1, int* __restrict__ pi1, float* __restrict__ pm2) {
    __shared__ __align__(16) char smem[36864];
    const int tid = threadIdx.x;
    const int khalf = blockIdx.x & 1;   // consecutive blocks share rows
    const int rowblk = blockIdx.x >> 1;
    const int l = tid & 63, w = tid >> 6;
    const int m31 = l & 31, h = l >> 5, h4 = h * 4;
    const int rowbase = rowblk * 128 + w * 32;
    const int tbase = khalf * 16; // this half's first k-tile

    uint4 p0, p1, p2, p3;
    stage_load(tbase, tid, chi, clo, p0, p1, p2, p3);
    *(float4*)(smem + 32768 + tid * 16) =
        *(const float4*)((const char*)c2 + tid * 16);

    uint4 bh0[8], bl0[8];
    load_row(latent + (size_t)(rowbase + m31) * D, h, bh0, bl0);
    stage_write(0, tid, p0, p1, p2, p3, smem);
    __syncthreads();

    float m1_0 = 3.4e38f, m2_0 = 3.4e38f;
    int i1_0 = khalf * 512;
    const float* c2l = (const float*)(smem + 32768);

#pragma unroll 1
    for (int t = 0; t < 16; ++t) {
        const int buf = t & 1;
        uint4 s0, s1, s2, s3;
        if (t + 1 < 16) stage_load(tbase + t + 1, tid, chi, clo, s0, s1, s2, s3);

        const int k0 = (tbase + t) * 32;
        f32x16 a0;
#pragma unroll
        for (int q = 0; q < 4; ++q) {
            float4 cq = *(const float4*)(c2l + k0 + 8 * q + h4);
            a0[4 * q + 0] = cq.x;
            a0[4 * q + 1] = cq.y;
            a0[4 * q + 2] = cq.z;
            a0[4 * q + 3] = cq.w;
        }

        const char* lhs = smem + buf * 16384;
#pragma unroll
        for (int c = 0; c < 8; ++c) {
            const int sw = (((2 * c + h) ^ (m31 & 15)) << 4) + m31 * 256;
            short8 ahi = *(const short8*)(lhs + sw);
            short8 alo = *(const short8*)(lhs + 8192 + sw);
            a0 = __builtin_amdgcn_mfma_f32_32x32x16_bf16(ahi, as_s8(bh0[c]), a0, 0, 0, 0);
            a0 = __builtin_amdgcn_mfma_f32_32x32x16_bf16(ahi, as_s8(bl0[c]), a0, 0, 0, 0);
            a0 = __builtin_amdgcn_mfma_f32_32x32x16_bf16(alo, as_s8(bh0[c]), a0, 0, 0, 0);
        }

#pragma unroll
        for (int q = 0; q < 4; ++q) {
#pragma unroll
            for (int j = 0; j < 4; ++j) {
                const int r = 4 * q + j;
                const int kk = k0 + 8 * q + j + h4;
                float v0 = a0[r];
                bool lt0 = v0 < m1_0;
                m2_0 = fminf(m2_0, fmaxf(v0, m1_0));
                m1_0 = fminf(m1_0, v0);
                i1_0 = lt0 ? kk : i1_0;
            }
        }

        if (t + 1 < 16) stage_write(buf ^ 1, tid, s0, s1, s2, s3, smem);
        __syncthreads();
    }

    // merge the two k-interleaves (lane l <-> l+32 hold same row); tie -> lower k
    {
        float om = __shfl_xor(m1_0, 32);
        int oi = __shfl_xor(i1_0, 32);
        float o2 = __shfl_xor(m2_0, 32);
        m2_0 = fminf(fminf(m2_0, o2), fmaxf(m1_0, om));
        bool take = (om < m1_0) || (om == m1_0 && oi < i1_0);
        m1_0 = fminf(m1_0, om);
        i1_0 = take ? oi : i1_0;
    }

    if (l < 32) {
        const int p = khalf * N + rowbase + l;
        pm1[p] = m1_0;
        pi1[p] = i1_0;
        pm2[p] = m2_0;
    }
}

// ---- merge halves: out + certify flag -> compact worklist ----
__global__ __launch_bounds__(256) void merge_flag_kernel(
    const float* __restrict__ pm1, const int* __restrict__ pi1,
    const float* __restrict__ pm2, int* __restrict__ out,
    int* __restrict__ counter, int* __restrict__ list) {
    const int row = blockIdx.x * 256 + threadIdx.x;
    const int l = threadIdx.x & 63;
    float m1a = pm1[row], m2a = pm2[row];
    int i1a = pi1[row];
    float m1b = pm1[N + row], m2b = pm2[N + row];
    int i1b = pi1[N + row];
    // half 0 has strictly lower k -> strict '<' keeps first occurrence
    bool take = m1b < m1a;
    float m1 = take ? m1b : m1a;
    int i1 = take ? i1b : i1a;
    float m2 = fminf(fminf(m2a, m2b), fmaxf(m1a, m1b));
    out[row] = i1;

    const bool flg = (m2 - m1) <= EPS2;
    unsigned long long bm = __ballot(flg);
    int cnt = __popcll(bm);
    int pos = 0;
    if (l == 0 && cnt) pos = atomicAdd(counter, cnt);
    pos = __shfl(pos, 0);
    if (flg)
        list[pos + __popcll(bm & ((1ull << l) - 1ull))] = row;
}

// ---- pass B: exact fp32 recompute, 4 rows/wave-task, coalesced coordsT ----
__global__ __launch_bounds__(256) void centroid_exact_kernel(
    const float* __restrict__ latent, const float* __restrict__ coordsT,
    const float* __restrict__ c2, const int* __restrict__ cnt_list,
    int* __restrict__ out) {
    const int count = cnt_list[0];
    const int* list = cnt_list + 16;
    const int lane = threadIdx.x & 63;
    const int gw = (blockIdx.x * 256 + threadIdx.x) >> 6;
    const int nwaves = gridDim.x * 4;
    // lane owns k = c*64 + lane, c = 0..15 (coalesced coordsT reads)

    for (int task = gw; task * 4 < count; task += nwaves) {
        const int base = task * 4;
        const int nr = min(4, count - base);
        const float* xp[4];
        int rows[4];
#pragma unroll
        for (int j = 0; j < 4; ++j) {
            int idx = base + (j < nr ? j : nr - 1);
            rows[j] = __builtin_amdgcn_readfirstlane(list[idx]);
            xp[j] = latent + (size_t)rows[j] * D;
        }

        float acc[16][4];
#pragma unroll
        for (int c = 0; c < 16; ++c) {
            float cc = c2[c * 64 + lane];
#pragma unroll
            for (int j = 0; j < 4; ++j) acc[c][j] = cc;
        }

#pragma unroll 1
        for (int d4 = 0; d4 < D / 4; ++d4) {
            float4 xq[4];
#pragma unroll
            for (int j = 0; j < 4; ++j)
                xq[j] = *(const float4*)(xp[j] + 4 * d4);
            float ct[4][16];
#pragma unroll
            for (int dd = 0; dd < 4; ++dd)
#pragma unroll
                for (int c = 0; c < 16; ++c)
                    ct[dd][c] = coordsT[(size_t)(4 * d4 + dd) * K + c * 64 + lane];
#pragma unroll
            for (int dd = 0; dd < 4; ++dd) {
#pragma unroll
                for (int c = 0; c < 16; ++c) {
#pragma unroll
                    for (int j = 0; j < 4; ++j) {
                        float xv = (dd == 0) ? xq[j].x
                                 : (dd == 1) ? xq[j].y
                                 : (dd == 2) ? xq[j].z : xq[j].w;
                        acc[c][j] = fmaf(-xv, ct[dd][c], acc[c][j]);
                    }
                }
            }
        }

#pragma unroll
        for (int j = 0; j < 4; ++j) {
            float m1 = acc[0][j];
            int i1 = lane;
#pragma unroll
            for (int c = 1; c < 16; ++c) {
                const int kk = c * 64 + lane;
                if (acc[c][j] < m1) { m1 = acc[c][j]; i1 = kk; }
            }
#pragma unroll
            for (int off = 1; off < 64; off <<= 1) {
                float om = __shfl_xor(m1, off);
                int oi = __shfl_xor(i1, off);
                if (om < m1 || (om == m1 && oi < i1)) { m1 = om; i1 = oi; }
            }
            if (lane == 0 && j < nr) out[rows[j]] = i1;
        }
    }
}

extern "C" void kernel_launch(void* const* d_in, const int* in_sizes, int n_in,
                              void* d_out, int out_size, void* d_ws, size_t ws_size,
                              hipStream_t stream) {
    const float* latent = (const float*)d_in[0];
    const float* coords = (const float*)d_in[1];
    int* out = (int*)d_out;

    char* ws = (char*)d_ws;
    size_t off = 0;
    float* c2 = (float*)(ws + off); off += 4096;
    uint* chi = (uint*)(ws + off); off += 262144;
    uint* clo = (uint*)(ws + off); off += 262144;
    float* coordsT = (float*)(ws + off); off += 524288;
    int* cnt_list = (int*)(ws + off); off += 64 + 524288;
    float* pm1 = (float*)(ws + off); off += (size_t)2 * N * 4;
    int* pi1 = (int*)(ws + off); off += (size_t)2 * N * 4;
    float* pm2 = (float*)(ws + off); off += (size_t)2 * N * 4;
    int* counter = cnt_list;
    int* list = cnt_list + 16;

    centroid_c2_kernel<<<(K + 255) / 256, 256, 0, stream>>>(coords, c2, counter);
    split_kernel<<<(K * D / 2) / 256, 256, 0, stream>>>(coords, chi, clo);
    {
        dim3 g(K / 64, D / 64);
        transpose_kernel<<<g, 256, 0, stream>>>(coords, coordsT);
    }
    // 128 rows/block x K-split x2: 2048 blocks; ~115 unified regs -> 4 waves/SIMD
    centroid_mfma_partial<<<2 * (N / 128), 256, 0, stream>>>(latent, chi, clo,
                                                             c2, pm1, pi1, pm2);
    merge_flag_kernel<<<N / 256, 256, 0, stream>>>(pm1, pi1, pm2, out, counter, list);
    centroid_exact_kernel<<<2048, 256, 0, stream>>>(latent, coordsT, c2, cnt_list, out);
}

// Round 12
// 180.964 us; speedup vs baseline: 1.0631x; 1.0631x over previous
//
#include <hip/hip_runtime.h>

// CentroidPool: argmin_k ||x_i - c_k||^2, N=131072, K=1024, D=128, fp32.
// = argmin_k (0.5||c_k||^2 - x.c_k).
// Pass A: MFMA bf16 hi/lo 3-term split, K-split x2, 128 rows/block,
// 32 rows/wave. Coords staged via global_load_lds from a PRE-SWIZZLED
// global buffer (linear LDS dest + inverse-swizzled source == swizzled
// read; guide rule #21). This removes the 16 staging VGPRs + ds_writes
// that made r11 spill under the (256,4) cap (VGPR=64, 31MB scratch).
// Live set ~105 <= 128 unified -> real 4 waves/SIMD.
// Merge kernel combines k-halves; pass B exact fp32 recompute (coalesced).

constexpr int N = 131072;
constexpr int K = 1024;
constexpr int D = 128;
constexpr float EPS2 = 0.05f; // certify margin >> worst-case approx err (~1e-3)

typedef __attribute__((ext_vector_type(8))) short short8;
typedef __attribute__((ext_vector_type(16))) float f32x16;

typedef const __attribute__((address_space(1))) uint* gas_uint;
typedef __attribute__((address_space(3))) uint* las_uint;

union U8 { uint4 u; short8 s; };
__device__ inline short8 as_s8(uint4 v) { U8 x; x.u = v; return x.s; }

__device__ inline uint bf16rne(float f) {
    uint u = __float_as_uint(f);
    return (u + 0x7fffu + ((u >> 16) & 1u)) >> 16;
}
__device__ inline void split2(float a, float b, uint& hi, uint& lo) {
    uint ha = bf16rne(a), hb = bf16rne(b);
    float la = a - __uint_as_float(ha << 16);
    float lb = b - __uint_as_float(hb << 16);
    hi = ha | (hb << 16);
    lo = bf16rne(la) | (bf16rne(lb) << 16);
}

// ---- precompute: 0.5*||c_k||^2; block 0 also zeroes the worklist counter ----
__global__ void centroid_c2_kernel(const float* __restrict__ coords,
                                   float* __restrict__ c2half,
                                   int* __restrict__ counter) {
    if (blockIdx.x == 0 && threadIdx.x == 0) counter[0] = 0;
    int k = blockIdx.x * 256 + threadIdx.x;
    if (k >= K) return;
    const float4* row = reinterpret_cast<const float4*>(coords + k * D);
    float s = 0.f;
#pragma unroll
    for (int i = 0; i < D / 4; ++i) {
        float4 v = row[i];
        s += v.x * v.x + v.y * v.y + v.z * v.z + v.w * v.w;
    }
    c2half[k] = 0.5f * s;
}

// ---- precompute: coords -> bf16 hi/lo, PRE-SWIZZLED per-tile layout ----
// tile kt (32 k): bytes [kt*16384, +16384): hi 8K then lo 8K.
// row m (k=kt*32+m), 16B-group g (d = 8g..8g+7): offset m*256 + ((g^(m&15))<<4).
__global__ void split_kernel(const float* __restrict__ coords,
                             uint* __restrict__ chilo) {
    int t = blockIdx.x * 256 + threadIdx.x; // dword index over K*64
    int k = t >> 6, dw = t & 63;
    int g = dw >> 2, sub = dw & 3;
    int kt = k >> 5, m = k & 31;
    float a = coords[k * D + 2 * dw], b = coords[k * D + 2 * dw + 1];
    uint hi, lo;
    split2(a, b, hi, lo);
    char* base = (char*)chilo + (size_t)kt * 16384 + m * 256 +
                 ((g ^ (m & 15)) << 4) + sub * 4;
    *(uint*)base = hi;
    *(uint*)(base + 8192) = lo;
}

// ---- precompute: coordsT[d][k] = coords[k][d] (LDS-tiled, coalesced) ----
__global__ __launch_bounds__(256) void transpose_kernel(
    const float* __restrict__ coords, float* __restrict__ coordsT) {
    __shared__ float tile[64][65];
    const int k0 = blockIdx.x * 64;
    const int d0 = blockIdx.y * 64;
    const int tx = threadIdx.x & 63, ty = threadIdx.x >> 6;
#pragma unroll
    for (int i = 0; i < 64; i += 4)
        tile[ty + i][tx] = coords[(size_t)(k0 + ty + i) * D + d0 + tx];
    __syncthreads();
#pragma unroll
    for (int i = 0; i < 64; i += 4)
        coordsT[(size_t)(d0 + ty + i) * K + k0 + tx] = tile[tx][ty + i];
}

__device__ inline void load_row(const float* rp, int h, uint4* bh, uint4* bl) {
#pragma unroll
    for (int c = 0; c < 8; ++c) {
        const float* p = rp + 16 * c + 8 * h;
        float4 u = *(const float4*)(p);
        float4 v = *(const float4*)(p + 4);
        uint h0, l0, h1, l1, h2, l2, h3, l3;
        split2(-u.x, -u.y, h0, l0);
        split2(-u.z, -u.w, h1, l1);
        split2(-v.x, -v.y, h2, l2);
        split2(-v.z, -v.w, h3, l3);
        bh[c] = make_uint4(h0, h1, h2, h3);
        bl[c] = make_uint4(l0, l1, l2, l3);
    }
}

// ---- pass A: MFMA approx over a K-half, 32 rows/wave, (m1,i1,m2) partials ----
__global__ __launch_bounds__(256, 4) void centroid_mfma_partial(
    const float* __restrict__ latent, const uint* __restrict__ chilo,
    const float* __restrict__ c2,
    float* __restrict__ pm1, int* __restrict__ pi1, float* __restrict__ pm2) {
    __shared__ __align__(16) char smem[36864]; // 2 x 16K dbuf + 4K c2
    const int tid = threadIdx.x;
    const int khalf = blockIdx.x & 1; // consecutive blocks share rows
    const int rowblk = blockIdx.x >> 1;
    const int l = tid & 63, w = tid >> 6;
    const int m31 = l & 31, h = l >> 5, h4 = h * 4;
    const int rowbase = rowblk * 128 + w * 32;
    const int tbase = khalf * 16; // this half's first k-tile

    // staging addresses: wave w copies bytes [w*4096, +4096) of each tile
    const int w4096 = w << 12;
    const char* gsrc0 = (const char*)chilo + (size_t)tbase * 16384 + w4096 +
                        ((tid & 63) << 4);
    // prologue: issue tile-0 staging
#pragma unroll
    for (int i = 0; i < 4; ++i)
        __builtin_amdgcn_global_load_lds((gas_uint)(gsrc0 + i * 1024),
                                         (las_uint)(smem + w4096 + i * 1024),
                                         16, 0, 0);
    // c2 -> LDS (4 KB at 32768)
    *(float4*)(smem + 32768 + tid * 16) =
        *(const float4*)((const char*)c2 + tid * 16);

    uint4 bh0[8], bl0[8];
    load_row(latent + (size_t)(rowbase + m31) * D, h, bh0, bl0);
    __syncthreads();

    float m1_0 = 3.4e38f, m2_0 = 3.4e38f;
    int i1_0 = khalf * 512;
    const float* c2l = (const float*)(smem + 32768);

#pragma unroll 2
    for (int t = 0; t < 16; ++t) {
        const int buf = t & 1;
        // issue next tile's staging into the other buffer
        if (t + 1 < 16) {
            const char* gs = gsrc0 + (size_t)(t + 1) * 16384;
            char* ls = smem + (buf ^ 1) * 16384 + w4096;
#pragma unroll
            for (int i = 0; i < 4; ++i)
                __builtin_amdgcn_global_load_lds((gas_uint)(gs + i * 1024),
                                                 (las_uint)(ls + i * 1024),
                                                 16, 0, 0);
        }

        const int k0 = (tbase + t) * 32;
        f32x16 a0;
#pragma unroll
        for (int q = 0; q < 4; ++q) {
            float4 cq = *(const float4*)(c2l + k0 + 8 * q + h4);
            a0[4 * q + 0] = cq.x;
            a0[4 * q + 1] = cq.y;
            a0[4 * q + 2] = cq.z;
            a0[4 * q + 3] = cq.w;
        }

        const char* lhs = smem + buf * 16384;
#pragma unroll
        for (int c = 0; c < 8; ++c) {
            const int sw = (((2 * c + h) ^ (m31 & 15)) << 4) + m31 * 256;
            short8 ahi = *(const short8*)(lhs + sw);
            short8 alo = *(const short8*)(lhs + 8192 + sw);
            a0 = __builtin_amdgcn_mfma_f32_32x32x16_bf16(ahi, as_s8(bh0[c]), a0, 0, 0, 0);
            a0 = __builtin_amdgcn_mfma_f32_32x32x16_bf16(ahi, as_s8(bl0[c]), a0, 0, 0, 0);
            a0 = __builtin_amdgcn_mfma_f32_32x32x16_bf16(alo, as_s8(bh0[c]), a0, 0, 0, 0);
        }

#pragma unroll
        for (int q = 0; q < 4; ++q) {
#pragma unroll
            for (int j = 0; j < 4; ++j) {
                const int r = 4 * q + j;
                const int kk = k0 + 8 * q + j + h4;
                float v0 = a0[r];
                bool lt0 = v0 < m1_0;
                m2_0 = fminf(m2_0, fmaxf(v0, m1_0));
                m1_0 = fminf(m1_0, v0);
                i1_0 = lt0 ? kk : i1_0;
            }
        }

        __syncthreads(); // drains vmcnt -> next buffer staged & this buf reusable
    }

    // merge the two k-interleaves (lane l <-> l+32 hold same row); tie -> lower k
    {
        float om = __shfl_xor(m1_0, 32);
        int oi = __shfl_xor(i1_0, 32);
        float o2 = __shfl_xor(m2_0, 32);
        m2_0 = fminf(fminf(m2_0, o2), fmaxf(m1_0, om));
        bool take = (om < m1_0) || (om == m1_0 && oi < i1_0);
        m1_0 = fminf(m1_0, om);
        i1_0 = take ? oi : i1_0;
    }

    if (l < 32) {
        const int p = khalf * N + rowbase + l;
        pm1[p] = m1_0;
        pi1[p] = i1_0;
        pm2[p] = m2_0;
    }
}

// ---- merge halves: out + certify flag -> compact worklist ----
__global__ __launch_bounds__(256) void merge_flag_kernel(
    const float* __restrict__ pm1, const int* __restrict__ pi1,
    const float* __restrict__ pm2, int* __restrict__ out,
    int* __restrict__ counter, int* __restrict__ list) {
    const int row = blockIdx.x * 256 + threadIdx.x;
    const int l = threadIdx.x & 63;
    float m1a = pm1[row], m2a = pm2[row];
    int i1a = pi1[row];
    float m1b = pm1[N + row], m2b = pm2[N + row];
    int i1b = pi1[N + row];
    // half 0 has strictly lower k -> strict '<' keeps first occurrence
    bool take = m1b < m1a;
    float m1 = take ? m1b : m1a;
    int i1 = take ? i1b : i1a;
    float m2 = fminf(fminf(m2a, m2b), fmaxf(m1a, m1b));
    out[row] = i1;

    const bool flg = (m2 - m1) <= EPS2;
    unsigned long long bm = __ballot(flg);
    int cnt = __popcll(bm);
    int pos = 0;
    if (l == 0 && cnt) pos = atomicAdd(counter, cnt);
    pos = __shfl(pos, 0);
    if (flg)
        list[pos + __popcll(bm & ((1ull << l) - 1ull))] = row;
}

// ---- pass B: exact fp32 recompute, 4 rows/wave-task, coalesced coordsT ----
__global__ __launch_bounds__(256) void centroid_exact_kernel(
    const float* __restrict__ latent, const float* __restrict__ coordsT,
    const float* __restrict__ c2, const int* __restrict__ cnt_list,
    int* __restrict__ out) {
    const int count = cnt_list[0];
    const int* list = cnt_list + 16;
    const int lane = threadIdx.x & 63;
    const int gw = (blockIdx.x * 256 + threadIdx.x) >> 6;
    const int nwaves = gridDim.x * 4;
    // lane owns k = c*64 + lane, c = 0..15 (coalesced coordsT reads)

    for (int task = gw; task * 4 < count; task += nwaves) {
        const int base = task * 4;
        const int nr = min(4, count - base);
        const float* xp[4];
        int rows[4];
#pragma unroll
        for (int j = 0; j < 4; ++j) {
            int idx = base + (j < nr ? j : nr - 1);
            rows[j] = __builtin_amdgcn_readfirstlane(list[idx]);
            xp[j] = latent + (size_t)rows[j] * D;
        }

        float acc[16][4];
#pragma unroll
        for (int c = 0; c < 16; ++c) {
            float cc = c2[c * 64 + lane];
#pragma unroll
            for (int j = 0; j < 4; ++j) acc[c][j] = cc;
        }

#pragma unroll 1
        for (int d4 = 0; d4 < D / 4; ++d4) {
            float4 xq[4];
#pragma unroll
            for (int j = 0; j < 4; ++j)
                xq[j] = *(const float4*)(xp[j] + 4 * d4);
            float ct[4][16];
#pragma unroll
            for (int dd = 0; dd < 4; ++dd)
#pragma unroll
                for (int c = 0; c < 16; ++c)
                    ct[dd][c] = coordsT[(size_t)(4 * d4 + dd) * K + c * 64 + lane];
#pragma unroll
            for (int dd = 0; dd < 4; ++dd) {
#pragma unroll
                for (int c = 0; c < 16; ++c) {
#pragma unroll
                    for (int j = 0; j < 4; ++j) {
                        float xv = (dd == 0) ? xq[j].x
                                 : (dd == 1) ? xq[j].y
                                 : (dd == 2) ? xq[j].z : xq[j].w;
                        acc[c][j] = fmaf(-xv, ct[dd][c], acc[c][j]);
                    }
                }
            }
        }

#pragma unroll
        for (int j = 0; j < 4; ++j) {
            float m1 = acc[0][j];
            int i1 = lane;
#pragma unroll
            for (int c = 1; c < 16; ++c) {
                const int kk = c * 64 + lane;
                if (acc[c][j] < m1) { m1 = acc[c][j]; i1 = kk; }
            }
#pragma unroll
            for (int off = 1; off < 64; off <<= 1) {
                float om = __shfl_xor(m1, off);
                int oi = __shfl_xor(i1, off);
                if (om < m1 || (om == m1 && oi < i1)) { m1 = om; i1 = oi; }
            }
            if (lane == 0 && j < nr) out[rows[j]] = i1;
        }
    }
}

extern "C" void kernel_launch(void* const* d_in, const int* in_sizes, int n_in,
                              void* d_out, int out_size, void* d_ws, size_t ws_size,
                              hipStream_t stream) {
    const float* latent = (const float*)d_in[0];
    const float* coords = (const float*)d_in[1];
    int* out = (int*)d_out;

    char* ws = (char*)d_ws;
    size_t off = 0;
    float* c2 = (float*)(ws + off); off += 4096;
    uint* chilo = (uint*)(ws + off); off += 524288;     // pre-swizzled hi/lo
    float* coordsT = (float*)(ws + off); off += 524288;
    int* cnt_list = (int*)(ws + off); off += 64 + 524288;
    float* pm1 = (float*)(ws + off); off += (size_t)2 * N * 4;
    int* pi1 = (int*)(ws + off); off += (size_t)2 * N * 4;
    float* pm2 = (float*)(ws + off); off += (size_t)2 * N * 4;
    int* counter = cnt_list;
    int* list = cnt_list + 16;

    centroid_c2_kernel<<<(K + 255) / 256, 256, 0, stream>>>(coords, c2, counter);
    split_kernel<<<(K * 64) / 256, 256, 0, stream>>>(coords, chilo);
    {
        dim3 g(K / 64, D / 64);
        transpose_kernel<<<g, 256, 0, stream>>>(coords, coordsT);
    }
    centroid_mfma_partial<<<2 * (N / 128), 256, 0, stream>>>(latent, chilo, c2,
                                                             pm1, pi1, pm2);
    merge_flag_kernel<<<N / 256, 256, 0, stream>>>(pm1, pi1, pm2, out, counter, list);
    centroid_exact_kernel<<<2048, 256, 0, stream>>>(latent, coordsT, c2, cnt_list, out);
}

// Round 13
// 173.940 us; speedup vs baseline: 1.1060x; 1.0404x over previous
//
#include <hip/hip_runtime.h>

// CentroidPool: argmin_k ||x_i - c_k||^2, N=131072, K=1024, D=128, fp32.
// = argmin_k (0.5||c_k||^2 - x.c_k).
// Pass A: MFMA bf16 hi/lo 3-term split, K-split x2, 256 rows/block,
// 64 rows/wave (nacc=2). r12 lesson: nacc=1 is LDS-throughput-bound
// (20 ds_read_b128/tile-wave = 240 cyc vs 192 MFMA cyc; floors 51 vs 41us).
// nacc=2 amortizes the A-fragment reads over 2x MFMAs (LDS floor ~26us,
// MFMA 41us -> MFMA-bound) and gives 2 independent acc chains. Coords
// staged via global_load_lds from the PRE-SWIZZLED global buffer (r12).
// 185 unified regs -> 2 waves/SIMD; (256,2) cap avoids the r9/r11 spills.
// Merge kernel combines k-halves; pass B exact fp32 recompute (coalesced).

constexpr int N = 131072;
constexpr int K = 1024;
constexpr int D = 128;
constexpr float EPS2 = 0.05f; // certify margin >> worst-case approx err (~1e-3)

typedef __attribute__((ext_vector_type(8))) short short8;
typedef __attribute__((ext_vector_type(16))) float f32x16;

typedef const __attribute__((address_space(1))) uint* gas_uint;
typedef __attribute__((address_space(3))) uint* las_uint;

union U8 { uint4 u; short8 s; };
__device__ inline short8 as_s8(uint4 v) { U8 x; x.u = v; return x.s; }

__device__ inline uint bf16rne(float f) {
    uint u = __float_as_uint(f);
    return (u + 0x7fffu + ((u >> 16) & 1u)) >> 16;
}
__device__ inline void split2(float a, float b, uint& hi, uint& lo) {
    uint ha = bf16rne(a), hb = bf16rne(b);
    float la = a - __uint_as_float(ha << 16);
    float lb = b - __uint_as_float(hb << 16);
    hi = ha | (hb << 16);
    lo = bf16rne(la) | (bf16rne(lb) << 16);
}

// ---- prep: counter zero + 0.5*||c_k||^2 + pre-swizzled bf16 hi/lo ----
// chilo tile kt (32 k): bytes [kt*16384,+16384): hi 8K then lo 8K.
// row m, 16B-group g: offset m*256 + ((g^(m&15))<<4).
__global__ __launch_bounds__(256) void prep_kernel(
    const float* __restrict__ coords, float* __restrict__ c2half,
    uint* __restrict__ chilo, int* __restrict__ counter) {
    if (blockIdx.x == 0 && threadIdx.x == 0) counter[0] = 0;
    const int k = blockIdx.x * 4 + (threadIdx.x >> 6); // one row per wave
    const int dw = threadIdx.x & 63;
    float a = coords[k * D + 2 * dw], b = coords[k * D + 2 * dw + 1];
    uint hi, lo;
    split2(a, b, hi, lo);
    const int g = dw >> 2, sub = dw & 3, kt = k >> 5, m = k & 31;
    char* base = (char*)chilo + (size_t)kt * 16384 + m * 256 +
                 ((g ^ (m & 15)) << 4) + sub * 4;
    *(uint*)base = hi;
    *(uint*)(base + 8192) = lo;
    float s = fmaf(a, a, b * b);
#pragma unroll
    for (int off = 1; off < 64; off <<= 1) s += __shfl_xor(s, off);
    if (dw == 0) c2half[k] = 0.5f * s;
}

// ---- precompute: coordsT[d][k] = coords[k][d] (LDS-tiled, coalesced) ----
__global__ __launch_bounds__(256) void transpose_kernel(
    const float* __restrict__ coords, float* __restrict__ coordsT) {
    __shared__ float tile[64][65];
    const int k0 = blockIdx.x * 64;
    const int d0 = blockIdx.y * 64;
    const int tx = threadIdx.x & 63, ty = threadIdx.x >> 6;
#pragma unroll
    for (int i = 0; i < 64; i += 4)
        tile[ty + i][tx] = coords[(size_t)(k0 + ty + i) * D + d0 + tx];
    __syncthreads();
#pragma unroll
    for (int i = 0; i < 64; i += 4)
        coordsT[(size_t)(d0 + ty + i) * K + k0 + tx] = tile[tx][ty + i];
}

__device__ inline void load_row(const float* rp, int h, uint4* bh, uint4* bl) {
#pragma unroll
    for (int c = 0; c < 8; ++c) {
        const float* p = rp + 16 * c + 8 * h;
        float4 u = *(const float4*)(p);
        float4 v = *(const float4*)(p + 4);
        uint h0, l0, h1, l1, h2, l2, h3, l3;
        split2(-u.x, -u.y, h0, l0);
        split2(-u.z, -u.w, h1, l1);
        split2(-v.x, -v.y, h2, l2);
        split2(-v.z, -v.w, h3, l3);
        bh[c] = make_uint4(h0, h1, h2, h3);
        bl[c] = make_uint4(l0, l1, l2, l3);
    }
}

// ---- pass A: MFMA approx over a K-half, 64 rows/wave, (m1,i1,m2) partials ----
__global__ __launch_bounds__(256, 2) void centroid_mfma_partial(
    const float* __restrict__ latent, const uint* __restrict__ chilo,
    const float* __restrict__ c2,
    float* __restrict__ pm1, int* __restrict__ pi1, float* __restrict__ pm2) {
    __shared__ __align__(16) char smem[36864]; // 2 x 16K dbuf + 4K c2
    const int tid = threadIdx.x;
    const int khalf = blockIdx.x & 1; // consecutive blocks share rows
    const int rowblk = blockIdx.x >> 1;
    const int l = tid & 63, w = tid >> 6;
    const int m31 = l & 31, h = l >> 5, h4 = h * 4;
    const int rowbase = rowblk * 256 + w * 64;
    const int tbase = khalf * 16; // this half's first k-tile

    // staging: wave w copies bytes [w*4096, +4096) of each 16 KB tile
    const int w4096 = w << 12;
    const char* gsrc0 = (const char*)chilo + (size_t)tbase * 16384 + w4096 +
                        ((tid & 63) << 4);
#pragma unroll
    for (int i = 0; i < 4; ++i)
        __builtin_amdgcn_global_load_lds((gas_uint)(gsrc0 + i * 1024),
                                         (las_uint)(smem + w4096 + i * 1024),
                                         16, 0, 0);
    // c2 -> LDS (4 KB at 32768)
    *(float4*)(smem + 32768 + tid * 16) =
        *(const float4*)((const char*)c2 + tid * 16);

    uint4 bh0[8], bl0[8], bh1[8], bl1[8];
    load_row(latent + (size_t)(rowbase + m31) * D, h, bh0, bl0);
    load_row(latent + (size_t)(rowbase + 32 + m31) * D, h, bh1, bl1);
    __syncthreads();

    float m1_0 = 3.4e38f, m2_0 = 3.4e38f, m1_1 = 3.4e38f, m2_1 = 3.4e38f;
    int i1_0 = khalf * 512, i1_1 = khalf * 512;
    const float* c2l = (const float*)(smem + 32768);

#pragma unroll 2
    for (int t = 0; t < 16; ++t) {
        const int buf = t & 1;
        if (t + 1 < 16) {
            const char* gs = gsrc0 + (size_t)(t + 1) * 16384;
            char* ls = smem + (buf ^ 1) * 16384 + w4096;
#pragma unroll
            for (int i = 0; i < 4; ++i)
                __builtin_amdgcn_global_load_lds((gas_uint)(gs + i * 1024),
                                                 (las_uint)(ls + i * 1024),
                                                 16, 0, 0);
        }

        const int k0 = (tbase + t) * 32;
        f32x16 a0, a1;
#pragma unroll
        for (int q = 0; q < 4; ++q) {
            float4 cq = *(const float4*)(c2l + k0 + 8 * q + h4);
            a0[4 * q + 0] = cq.x;
            a0[4 * q + 1] = cq.y;
            a0[4 * q + 2] = cq.z;
            a0[4 * q + 3] = cq.w;
        }
        a1 = a0;

        const char* lhs = smem + buf * 16384;
#pragma unroll
        for (int c = 0; c < 8; ++c) {
            const int sw = (((2 * c + h) ^ (m31 & 15)) << 4) + m31 * 256;
            short8 ahi = *(const short8*)(lhs + sw);
            short8 alo = *(const short8*)(lhs + 8192 + sw);
            a0 = __builtin_amdgcn_mfma_f32_32x32x16_bf16(ahi, as_s8(bh0[c]), a0, 0, 0, 0);
            a1 = __builtin_amdgcn_mfma_f32_32x32x16_bf16(ahi, as_s8(bh1[c]), a1, 0, 0, 0);
            a0 = __builtin_amdgcn_mfma_f32_32x32x16_bf16(ahi, as_s8(bl0[c]), a0, 0, 0, 0);
            a1 = __builtin_amdgcn_mfma_f32_32x32x16_bf16(ahi, as_s8(bl1[c]), a1, 0, 0, 0);
            a0 = __builtin_amdgcn_mfma_f32_32x32x16_bf16(alo, as_s8(bh0[c]), a0, 0, 0, 0);
            a1 = __builtin_amdgcn_mfma_f32_32x32x16_bf16(alo, as_s8(bh1[c]), a1, 0, 0, 0);
        }

#pragma unroll
        for (int q = 0; q < 4; ++q) {
#pragma unroll
            for (int j = 0; j < 4; ++j) {
                const int r = 4 * q + j;
                const int kk = k0 + 8 * q + j + h4;
                float v0 = a0[r], v1 = a1[r];
                bool lt0 = v0 < m1_0, lt1 = v1 < m1_1;
                m2_0 = fminf(m2_0, fmaxf(v0, m1_0));
                m2_1 = fminf(m2_1, fmaxf(v1, m1_1));
                m1_0 = fminf(m1_0, v0);
                m1_1 = fminf(m1_1, v1);
                i1_0 = lt0 ? kk : i1_0;
                i1_1 = lt1 ? kk : i1_1;
            }
        }

        __syncthreads(); // next buffer staged & this buf reusable
    }

    // merge the two k-interleaves (lane l <-> l+32 hold same row); tie -> lower k
    {
        float om = __shfl_xor(m1_0, 32);
        int oi = __shfl_xor(i1_0, 32);
        float o2 = __shfl_xor(m2_0, 32);
        m2_0 = fminf(fminf(m2_0, o2), fmaxf(m1_0, om));
        bool take = (om < m1_0) || (om == m1_0 && oi < i1_0);
        m1_0 = fminf(m1_0, om);
        i1_0 = take ? oi : i1_0;
    }
    {
        float om = __shfl_xor(m1_1, 32);
        int oi = __shfl_xor(i1_1, 32);
        float o2 = __shfl_xor(m2_1, 32);
        m2_1 = fminf(fminf(m2_1, o2), fmaxf(m1_1, om));
        bool take = (om < m1_1) || (om == m1_1 && oi < i1_1);
        m1_1 = fminf(m1_1, om);
        i1_1 = take ? oi : i1_1;
    }

    if (l < 32) {
        const int p = khalf * N + rowbase + l;
        pm1[p] = m1_0;
        pi1[p] = i1_0;
        pm2[p] = m2_0;
        pm1[p + 32] = m1_1;
        pi1[p + 32] = i1_1;
        pm2[p + 32] = m2_1;
    }
}

// ---- merge halves: out + certify flag -> compact worklist ----
__global__ __launch_bounds__(256) void merge_flag_kernel(
    const float* __restrict__ pm1, const int* __restrict__ pi1,
    const float* __restrict__ pm2, int* __restrict__ out,
    int* __restrict__ counter, int* __restrict__ list) {
    const int row = blockIdx.x * 256 + threadIdx.x;
    const int l = threadIdx.x & 63;
    float m1a = pm1[row], m2a = pm2[row];
    int i1a = pi1[row];
    float m1b = pm1[N + row], m2b = pm2[N + row];
    int i1b = pi1[N + row];
    // half 0 has strictly lower k -> strict '<' keeps first occurrence
    bool take = m1b < m1a;
    float m1 = take ? m1b : m1a;
    int i1 = take ? i1b : i1a;
    float m2 = fminf(fminf(m2a, m2b), fmaxf(m1a, m1b));
    out[row] = i1;

    const bool flg = (m2 - m1) <= EPS2;
    unsigned long long bm = __ballot(flg);
    int cnt = __popcll(bm);
    int pos = 0;
    if (l == 0 && cnt) pos = atomicAdd(counter, cnt);
    pos = __shfl(pos, 0);
    if (flg)
        list[pos + __popcll(bm & ((1ull << l) - 1ull))] = row;
}

// ---- pass B: exact fp32 recompute, 4 rows/wave-task, coalesced coordsT ----
__global__ __launch_bounds__(256) void centroid_exact_kernel(
    const float* __restrict__ latent, const float* __restrict__ coordsT,
    const float* __restrict__ c2, const int* __restrict__ cnt_list,
    int* __restrict__ out) {
    const int count = cnt_list[0];
    const int* list = cnt_list + 16;
    const int lane = threadIdx.x & 63;
    const int gw = (blockIdx.x * 256 + threadIdx.x) >> 6;
    const int nwaves = gridDim.x * 4;
    // lane owns k = c*64 + lane, c = 0..15 (coalesced coordsT reads)

    for (int task = gw; task * 4 < count; task += nwaves) {
        const int base = task * 4;
        const int nr = min(4, count - base);
        const float* xp[4];
        int rows[4];
#pragma unroll
        for (int j = 0; j < 4; ++j) {
            int idx = base + (j < nr ? j : nr - 1);
            rows[j] = __builtin_amdgcn_readfirstlane(list[idx]);
            xp[j] = latent + (size_t)rows[j] * D;
        }

        float acc[16][4];
#pragma unroll
        for (int c = 0; c < 16; ++c) {
            float cc = c2[c * 64 + lane];
#pragma unroll
            for (int j = 0; j < 4; ++j) acc[c][j] = cc;
        }

#pragma unroll 1
        for (int d4 = 0; d4 < D / 4; ++d4) {
            float4 xq[4];
#pragma unroll
            for (int j = 0; j < 4; ++j)
                xq[j] = *(const float4*)(xp[j] + 4 * d4);
            float ct[4][16];
#pragma unroll
            for (int dd = 0; dd < 4; ++dd)
#pragma unroll
                for (int c = 0; c < 16; ++c)
                    ct[dd][c] = coordsT[(size_t)(4 * d4 + dd) * K + c * 64 + lane];
#pragma unroll
            for (int dd = 0; dd < 4; ++dd) {
#pragma unroll
                for (int c = 0; c < 16; ++c) {
#pragma unroll
                    for (int j = 0; j < 4; ++j) {
                        float xv = (dd == 0) ? xq[j].x
                                 : (dd == 1) ? xq[j].y
                                 : (dd == 2) ? xq[j].z : xq[j].w;
                        acc[c][j] = fmaf(-xv, ct[dd][c], acc[c][j]);
                    }
                }
            }
        }

#pragma unroll
        for (int j = 0; j < 4; ++j) {
            float m1 = acc[0][j];
            int i1 = lane;
#pragma unroll
            for (int c = 1; c < 16; ++c) {
                const int kk = c * 64 + lane;
                if (acc[c][j] < m1) { m1 = acc[c][j]; i1 = kk; }
            }
#pragma unroll
            for (int off = 1; off < 64; off <<= 1) {
                float om = __shfl_xor(m1, off);
                int oi = __shfl_xor(i1, off);
                if (om < m1 || (om == m1 && oi < i1)) { m1 = om; i1 = oi; }
            }
            if (lane == 0 && j < nr) out[rows[j]] = i1;
        }
    }
}

extern "C" void kernel_launch(void* const* d_in, const int* in_sizes, int n_in,
                              void* d_out, int out_size, void* d_ws, size_t ws_size,
                              hipStream_t stream) {
    const float* latent = (const float*)d_in[0];
    const float* coords = (const float*)d_in[1];
    int* out = (int*)d_out;

    char* ws = (char*)d_ws;
    size_t off = 0;
    float* c2 = (float*)(ws + off); off += 4096;
    uint* chilo = (uint*)(ws + off); off += 524288;     // pre-swizzled hi/lo
    float* coordsT = (float*)(ws + off); off += 524288;
    int* cnt_list = (int*)(ws + off); off += 64 + 524288;
    float* pm1 = (float*)(ws + off); off += (size_t)2 * N * 4;
    int* pi1 = (int*)(ws + off); off += (size_t)2 * N * 4;
    float* pm2 = (float*)(ws + off); off += (size_t)2 * N * 4;
    int* counter = cnt_list;
    int* list = cnt_list + 16;

    prep_kernel<<<K / 4, 256, 0, stream>>>(coords, c2, chilo, counter);
    {
        dim3 g(K / 64, D / 64);
        transpose_kernel<<<g, 256, 0, stream>>>(coords, coordsT);
    }
    // 256 rows/block x K-split x2: 1024 blocks, 2 waves/SIMD (185 regs)
    centroid_mfma_partial<<<2 * (N / 256), 256, 0, stream>>>(latent, chilo, c2,
                                                             pm1, pi1, pm2);
    merge_flag_kernel<<<N / 256, 256, 0, stream>>>(pm1, pi1, pm2, out, counter, list);
    centroid_exact_kernel<<<2048, 256, 0, stream>>>(latent, coordsT, c2, cnt_list, out);
}

// Round 14
// 150.874 us; speedup vs baseline: 1.2751x; 1.1529x over previous
//
#include <hip/hip_runtime.h>

// CentroidPool: argmin_k ||x_i - c_k||^2, N=131072, K=1024, D=128, fp32.
// = argmin_k (0.5||c_k||^2 - x.c_k).
// Pass A: bf16 hi/lo 3-term split on mfma_f32_16x16x32 (8 independent
// acc chains/wave of depth 12, vs 32x32's 2 chains of depth 24 -- r8..r13
// were pinned at ~105us / 42% MfmaUtil across every occupancy/staging
// config => MFMA dep-chain latency bound). 64 rows/wave, full K per block
// (no k-split, no merge kernel): block writes out + compact worklist.
// Coords staged via global_load_lds from PRE-SWIZZLED buffer (r12).
// Pass B: exact fp32 recompute (coalesced coordsT), bit-identical chain.

constexpr int N = 131072;
constexpr int K = 1024;
constexpr int D = 128;
constexpr float EPS2 = 0.05f; // certify margin >> worst-case approx err (~1e-3)

typedef __attribute__((ext_vector_type(8))) short short8;
typedef __attribute__((ext_vector_type(4))) float f32x4;

typedef const __attribute__((address_space(1))) uint* gas_uint;
typedef __attribute__((address_space(3))) uint* las_uint;

union U8 { uint4 u; short8 s; };
__device__ inline short8 as_s8(uint4 v) { U8 x; x.u = v; return x.s; }

__device__ inline uint bf16rne(float f) {
    uint u = __float_as_uint(f);
    return (u + 0x7fffu + ((u >> 16) & 1u)) >> 16;
}
__device__ inline void split2(float a, float b, uint& hi, uint& lo) {
    uint ha = bf16rne(a), hb = bf16rne(b);
    float la = a - __uint_as_float(ha << 16);
    float lb = b - __uint_as_float(hb << 16);
    hi = ha | (hb << 16);
    lo = bf16rne(la) | (bf16rne(lb) << 16);
}

// ---- prep: counter zero + 0.5*||c_k||^2 + pre-swizzled bf16 hi/lo ----
// chilo tile kt (32 k): bytes [kt*16384,+16384): hi 8K then lo 8K.
// row m, 16B-group g: offset m*256 + ((g^(m&15))<<4).
__global__ __launch_bounds__(256) void prep_kernel(
    const float* __restrict__ coords, float* __restrict__ c2half,
    uint* __restrict__ chilo, int* __restrict__ counter) {
    if (blockIdx.x == 0 && threadIdx.x == 0) counter[0] = 0;
    const int k = blockIdx.x * 4 + (threadIdx.x >> 6); // one row per wave
    const int dw = threadIdx.x & 63;
    float a = coords[k * D + 2 * dw], b = coords[k * D + 2 * dw + 1];
    uint hi, lo;
    split2(a, b, hi, lo);
    const int g = dw >> 2, sub = dw & 3, kt = k >> 5, m = k & 31;
    char* base = (char*)chilo + (size_t)kt * 16384 + m * 256 +
                 ((g ^ (m & 15)) << 4) + sub * 4;
    *(uint*)base = hi;
    *(uint*)(base + 8192) = lo;
    float s = fmaf(a, a, b * b);
#pragma unroll
    for (int off = 1; off < 64; off <<= 1) s += __shfl_xor(s, off);
    if (dw == 0) c2half[k] = 0.5f * s;
}

// ---- precompute: coordsT[d][k] = coords[k][d] (LDS-tiled, coalesced) ----
__global__ __launch_bounds__(256) void transpose_kernel(
    const float* __restrict__ coords, float* __restrict__ coordsT) {
    __shared__ float tile[64][65];
    const int k0 = blockIdx.x * 64;
    const int d0 = blockIdx.y * 64;
    const int tx = threadIdx.x & 63, ty = threadIdx.x >> 6;
#pragma unroll
    for (int i = 0; i < 64; i += 4)
        tile[ty + i][tx] = coords[(size_t)(k0 + ty + i) * D + d0 + tx];
    __syncthreads();
#pragma unroll
    for (int i = 0; i < 64; i += 4)
        coordsT[(size_t)(d0 + ty + i) * K + k0 + tx] = tile[tx][ty + i];
}

// ---- pass A: 16x16x32 MFMA approx, 64 rows/wave, out + worklist direct ----
__global__ __launch_bounds__(256, 2) void centroid_mfma_kernel(
    const float* __restrict__ latent, const uint* __restrict__ chilo,
    const float* __restrict__ c2, int* __restrict__ out,
    int* __restrict__ counter, int* __restrict__ list) {
    __shared__ __align__(16) char smem[36864]; // 2 x 16K dbuf + 4K c2
    const int tid = threadIdx.x;
    const int l = tid & 63, w = tid >> 6;
    const int l15 = l & 15, l4 = l >> 4; // l4 in 0..3
    const int rowbase = blockIdx.x * 256 + w * 64;

    // staging: wave w copies bytes [w*4096, +4096) of each 16 KB k-tile
    const int w4096 = w << 12;
    const char* gsrc0 = (const char*)chilo + w4096 + ((tid & 63) << 4);
#pragma unroll
    for (int i = 0; i < 4; ++i)
        __builtin_amdgcn_global_load_lds((gas_uint)(gsrc0 + i * 1024),
                                         (las_uint)(smem + w4096 + i * 1024),
                                         16, 0, 0);
    // c2 -> LDS (4 KB at 32768)
    *(float4*)(smem + 32768 + tid * 16) =
        *(const float4*)((const char*)c2 + tid * 16);

    // B-frags: lane holds latent[rowbase + grp*16 + l15][32s + l4*8 .. +8]
    // negated, bf16 hi/lo. 4 grps x 4 d-slices x (hi,lo) = 128 VGPRs.
    uint4 bh[4][4], bl[4][4];
#pragma unroll
    for (int grp = 0; grp < 4; ++grp) {
        const float* rp =
            latent + (size_t)(rowbase + grp * 16 + l15) * D + l4 * 8;
#pragma unroll
        for (int s = 0; s < 4; ++s) {
            float4 u = *(const float4*)(rp + 32 * s);
            float4 v = *(const float4*)(rp + 32 * s + 4);
            uint h0, o0, h1, o1, h2, o2, h3, o3;
            split2(-u.x, -u.y, h0, o0);
            split2(-u.z, -u.w, h1, o1);
            split2(-v.x, -v.y, h2, o2);
            split2(-v.z, -v.w, h3, o3);
            bh[grp][s] = make_uint4(h0, h1, h2, h3);
            bl[grp][s] = make_uint4(o0, o1, o2, o3);
        }
    }
    __syncthreads();

    float m1[4] = {3.4e38f, 3.4e38f, 3.4e38f, 3.4e38f};
    float m2[4] = {3.4e38f, 3.4e38f, 3.4e38f, 3.4e38f};
    int i1[4] = {0, 0, 0, 0};
    const float* c2l = (const float*)(smem + 32768);

#pragma unroll 1
    for (int t = 0; t < 32; ++t) {
        const int buf = t & 1;
        if (t + 1 < 32) {
            const char* gs = gsrc0 + (size_t)(t + 1) * 16384;
            char* ls = smem + (buf ^ 1) * 16384 + w4096;
#pragma unroll
            for (int i = 0; i < 4; ++i)
                __builtin_amdgcn_global_load_lds((gas_uint)(gs + i * 1024),
                                                 (las_uint)(ls + i * 1024),
                                                 16, 0, 0);
        }

        const int k0 = t * 32;
        // acc[ks][grp]: D[k = k0+ks*16+l4*4+r][row = rowbase+grp*16+l15]
        f32x4 acc[2][4];
#pragma unroll
        for (int ks = 0; ks < 2; ++ks) {
            float4 cq = *(const float4*)(c2l + k0 + ks * 16 + l4 * 4);
#pragma unroll
            for (int grp = 0; grp < 4; ++grp) {
                acc[ks][grp][0] = cq.x;
                acc[ks][grp][1] = cq.y;
                acc[ks][grp][2] = cq.z;
                acc[ks][grp][3] = cq.w;
            }
        }

        const char* lhs = smem + buf * 16384;
#pragma unroll
        for (int s = 0; s < 4; ++s) {
            short8 ahi[2], alo[2];
#pragma unroll
            for (int ks = 0; ks < 2; ++ks) {
                const int m = ks * 16 + l15;
                const int g = l4 + 4 * s;
                const int sw = m * 256 + ((g ^ (m & 15)) << 4);
                ahi[ks] = *(const short8*)(lhs + sw);
                alo[ks] = *(const short8*)(lhs + 8192 + sw);
            }
#pragma unroll
            for (int ks = 0; ks < 2; ++ks) {
#pragma unroll
                for (int grp = 0; grp < 4; ++grp) {
                    acc[ks][grp] = __builtin_amdgcn_mfma_f32_16x16x32_bf16(
                        ahi[ks], as_s8(bh[grp][s]), acc[ks][grp], 0, 0, 0);
                    acc[ks][grp] = __builtin_amdgcn_mfma_f32_16x16x32_bf16(
                        ahi[ks], as_s8(bl[grp][s]), acc[ks][grp], 0, 0, 0);
                    acc[ks][grp] = __builtin_amdgcn_mfma_f32_16x16x32_bf16(
                        alo[ks], as_s8(bh[grp][s]), acc[ks][grp], 0, 0, 0);
                }
            }
        }

        // insert 8 k-values per row-state, ascending k (first-occ tie-break)
#pragma unroll
        for (int ks = 0; ks < 2; ++ks) {
#pragma unroll
            for (int r = 0; r < 4; ++r) {
                const int kk = k0 + ks * 16 + l4 * 4 + r;
#pragma unroll
                for (int grp = 0; grp < 4; ++grp) {
                    float v = acc[ks][grp][r];
                    bool lt = v < m1[grp];
                    m2[grp] = fminf(m2[grp], fmaxf(v, m1[grp]));
                    m1[grp] = fminf(m1[grp], v);
                    i1[grp] = lt ? kk : i1[grp];
                }
            }
        }

        __syncthreads(); // next buffer staged & this buf reusable
    }

    // merge k-partitions: lanes l, l^16, l^32, l^48 hold same rows (l15)
#pragma unroll
    for (int off = 16; off <= 32; off <<= 1) {
#pragma unroll
        for (int grp = 0; grp < 4; ++grp) {
            float om = __shfl_xor(m1[grp], off);
            int oi = __shfl_xor(i1[grp], off);
            float o2 = __shfl_xor(m2[grp], off);
            m2[grp] = fminf(fminf(m2[grp], o2), fmaxf(m1[grp], om));
            bool take = (om < m1[grp]) || (om == m1[grp] && oi < i1[grp]);
            m1[grp] = fminf(m1[grp], om);
            i1[grp] = take ? oi : i1[grp];
        }
    }

    // lanes 0..15 own rows rowbase + grp*16 + l
    bool flg[4];
    unsigned long long bm[4];
    int total = 0;
#pragma unroll
    for (int grp = 0; grp < 4; ++grp) {
        flg[grp] = (l < 16) && ((m2[grp] - m1[grp]) <= EPS2);
        bm[grp] = __ballot(flg[grp]);
        total += __popcll(bm[grp]);
    }
    int pos = 0;
    if (l == 0 && total) pos = atomicAdd(counter, total);
    pos = __shfl(pos, 0);
    if (l < 16) {
        int run = pos;
#pragma unroll
        for (int grp = 0; grp < 4; ++grp) {
            out[rowbase + grp * 16 + l] = i1[grp];
            if (flg[grp])
                list[run + __popcll(bm[grp] & ((1ull << l) - 1ull))] =
                    rowbase + grp * 16 + l;
            run += __popcll(bm[grp]);
        }
    }
}

// ---- pass B: exact fp32 recompute, 4 rows/wave-task, coalesced coordsT ----
__global__ __launch_bounds__(256) void centroid_exact_kernel(
    const float* __restrict__ latent, const float* __restrict__ coordsT,
    const float* __restrict__ c2, const int* __restrict__ cnt_list,
    int* __restrict__ out) {
    const int count = cnt_list[0];
    const int* list = cnt_list + 16;
    const int lane = threadIdx.x & 63;
    const int gw = (blockIdx.x * 256 + threadIdx.x) >> 6;
    const int nwaves = gridDim.x * 4;
    // lane owns k = c*64 + lane, c = 0..15 (coalesced coordsT reads)

    for (int task = gw; task * 4 < count; task += nwaves) {
        const int base = task * 4;
        const int nr = min(4, count - base);
        const float* xp[4];
        int rows[4];
#pragma unroll
        for (int j = 0; j < 4; ++j) {
            int idx = base + (j < nr ? j : nr - 1);
            rows[j] = __builtin_amdgcn_readfirstlane(list[idx]);
            xp[j] = latent + (size_t)rows[j] * D;
        }

        float acc[16][4];
#pragma unroll
        for (int c = 0; c < 16; ++c) {
            float cc = c2[c * 64 + lane];
#pragma unroll
            for (int j = 0; j < 4; ++j) acc[c][j] = cc;
        }

#pragma unroll 1
        for (int d4 = 0; d4 < D / 4; ++d4) {
            float4 xq[4];
#pragma unroll
            for (int j = 0; j < 4; ++j)
                xq[j] = *(const float4*)(xp[j] + 4 * d4);
            float ct[4][16];
#pragma unroll
            for (int dd = 0; dd < 4; ++dd)
#pragma unroll
                for (int c = 0; c < 16; ++c)
                    ct[dd][c] = coordsT[(size_t)(4 * d4 + dd) * K + c * 64 + lane];
#pragma unroll
            for (int dd = 0; dd < 4; ++dd) {
#pragma unroll
                for (int c = 0; c < 16; ++c) {
#pragma unroll
                    for (int j = 0; j < 4; ++j) {
                        float xv = (dd == 0) ? xq[j].x
                                 : (dd == 1) ? xq[j].y
                                 : (dd == 2) ? xq[j].z : xq[j].w;
                        acc[c][j] = fmaf(-xv, ct[dd][c], acc[c][j]);
                    }
                }
            }
        }

#pragma unroll
        for (int j = 0; j < 4; ++j) {
            float m1 = acc[0][j];
            int i1 = lane;
#pragma unroll
            for (int c = 1; c < 16; ++c) {
                const int kk = c * 64 + lane;
                if (acc[c][j] < m1) { m1 = acc[c][j]; i1 = kk; }
            }
#pragma unroll
            for (int off = 1; off < 64; off <<= 1) {
                float om = __shfl_xor(m1, off);
                int oi = __shfl_xor(i1, off);
                if (om < m1 || (om == m1 && oi < i1)) { m1 = om; i1 = oi; }
            }
            if (lane == 0 && j < nr) out[rows[j]] = i1;
        }
    }
}

extern "C" void kernel_launch(void* const* d_in, const int* in_sizes, int n_in,
                              void* d_out, int out_size, void* d_ws, size_t ws_size,
                              hipStream_t stream) {
    const float* latent = (const float*)d_in[0];
    const float* coords = (const float*)d_in[1];
    int* out = (int*)d_out;

    char* ws = (char*)d_ws;
    size_t off = 0;
    float* c2 = (float*)(ws + off); off += 4096;
    uint* chilo = (uint*)(ws + off); off += 524288;     // pre-swizzled hi/lo
    float* coordsT = (float*)(ws + off); off += 524288;
    int* cnt_list = (int*)(ws + off); off += 64 + 524288;
    int* counter = cnt_list;
    int* list = cnt_list + 16;

    prep_kernel<<<K / 4, 256, 0, stream>>>(coords, c2, chilo, counter);
    {
        dim3 g(K / 64, D / 64);
        transpose_kernel<<<g, 256, 0, stream>>>(coords, coordsT);
    }
    // 256 rows/block, full K per block: 512 blocks, 2 blocks/CU
    centroid_mfma_kernel<<<N / 256, 256, 0, stream>>>(latent, chilo, c2, out,
                                                      counter, list);
    centroid_exact_kernel<<<2048, 256, 0, stream>>>(latent, coordsT, c2,
                                                    cnt_list, out);
}

// Round 15
// 144.427 us; speedup vs baseline: 1.3321x; 1.0446x over previous
//
#include <hip/hip_runtime.h>

// CentroidPool: argmin_k ||x_i - c_k||^2, N=131072, K=1024, D=128, fp32.
// = argmin_k (0.5||c_k||^2 - x.c_k).
// Pass A: bf16 hi/lo 3-term split on mfma_f32_16x16x32, 64 rows/wave,
// full K per block. r8-r14 pinned at ~105us / 40% MfmaUtil across all
// shape/occupancy/staging configs => the 2-barrier vmcnt(0)-drain loop
// structure is the ceiling (guide m97/m233). This round: counted-vmcnt
// schedule (T3/T4) -- vmcnt(4) keeps next tile's global_load_lds in
// flight across barriers, never draining to 0 in the main loop -- plus
// s_setprio(1) around the MFMA cluster (T5).
// Pass B: exact fp32 recompute (coalesced coordsT), bit-identical chain.

constexpr int N = 131072;
constexpr int K = 1024;
constexpr int D = 128;
constexpr float EPS2 = 0.05f; // certify margin >> worst-case approx err (~1e-3)

typedef __attribute__((ext_vector_type(8))) short short8;
typedef __attribute__((ext_vector_type(4))) float f32x4;

typedef const __attribute__((address_space(1))) uint* gas_uint;
typedef __attribute__((address_space(3))) uint* las_uint;

union U8 { uint4 u; short8 s; };
__device__ inline short8 as_s8(uint4 v) { U8 x; x.u = v; return x.s; }

__device__ inline uint bf16rne(float f) {
    uint u = __float_as_uint(f);
    return (u + 0x7fffu + ((u >> 16) & 1u)) >> 16;
}
__device__ inline void split2(float a, float b, uint& hi, uint& lo) {
    uint ha = bf16rne(a), hb = bf16rne(b);
    float la = a - __uint_as_float(ha << 16);
    float lb = b - __uint_as_float(hb << 16);
    hi = ha | (hb << 16);
    lo = bf16rne(la) | (bf16rne(lb) << 16);
}

// ---- prep: counter zero + 0.5*||c_k||^2 + pre-swizzled bf16 hi/lo ----
// chilo tile kt (32 k): bytes [kt*16384,+16384): hi 8K then lo 8K.
// row m, 16B-group g: offset m*256 + ((g^(m&15))<<4).
__global__ __launch_bounds__(256) void prep_kernel(
    const float* __restrict__ coords, float* __restrict__ c2half,
    uint* __restrict__ chilo, int* __restrict__ counter) {
    if (blockIdx.x == 0 && threadIdx.x == 0) counter[0] = 0;
    const int k = blockIdx.x * 4 + (threadIdx.x >> 6); // one row per wave
    const int dw = threadIdx.x & 63;
    float a = coords[k * D + 2 * dw], b = coords[k * D + 2 * dw + 1];
    uint hi, lo;
    split2(a, b, hi, lo);
    const int g = dw >> 2, sub = dw & 3, kt = k >> 5, m = k & 31;
    char* base = (char*)chilo + (size_t)kt * 16384 + m * 256 +
                 ((g ^ (m & 15)) << 4) + sub * 4;
    *(uint*)base = hi;
    *(uint*)(base + 8192) = lo;
    float s = fmaf(a, a, b * b);
#pragma unroll
    for (int off = 1; off < 64; off <<= 1) s += __shfl_xor(s, off);
    if (dw == 0) c2half[k] = 0.5f * s;
}

// ---- precompute: coordsT[d][k] = coords[k][d] (LDS-tiled, coalesced) ----
__global__ __launch_bounds__(256) void transpose_kernel(
    const float* __restrict__ coords, float* __restrict__ coordsT) {
    __shared__ float tile[64][65];
    const int k0 = blockIdx.x * 64;
    const int d0 = blockIdx.y * 64;
    const int tx = threadIdx.x & 63, ty = threadIdx.x >> 6;
#pragma unroll
    for (int i = 0; i < 64; i += 4)
        tile[ty + i][tx] = coords[(size_t)(k0 + ty + i) * D + d0 + tx];
    __syncthreads();
#pragma unroll
    for (int i = 0; i < 64; i += 4)
        coordsT[(size_t)(d0 + ty + i) * K + k0 + tx] = tile[tx][ty + i];
}

// ---- pass A: 16x16x32 MFMA, counted-vmcnt pipeline, out + worklist ----
__global__ __launch_bounds__(256, 2) void centroid_mfma_kernel(
    const float* __restrict__ latent, const uint* __restrict__ chilo,
    const float* __restrict__ c2, int* __restrict__ out,
    int* __restrict__ counter, int* __restrict__ list) {
    __shared__ __align__(16) char smem[36864]; // 2 x 16K dbuf + 4K c2
    const int tid = threadIdx.x;
    const int l = tid & 63, w = tid >> 6;
    const int l15 = l & 15, l4 = l >> 4; // l4 in 0..3
    const int rowbase = blockIdx.x * 256 + w * 64;

    // B-frags FIRST (their result-waits must not entangle with staging):
    // lane holds latent[rowbase + grp*16 + l15][32s + l4*8 .. +8], negated.
    uint4 bh[4][4], bl[4][4];
#pragma unroll
    for (int grp = 0; grp < 4; ++grp) {
        const float* rp =
            latent + (size_t)(rowbase + grp * 16 + l15) * D + l4 * 8;
#pragma unroll
        for (int s = 0; s < 4; ++s) {
            float4 u = *(const float4*)(rp + 32 * s);
            float4 v = *(const float4*)(rp + 32 * s + 4);
            uint h0, o0, h1, o1, h2, o2, h3, o3;
            split2(-u.x, -u.y, h0, o0);
            split2(-u.z, -u.w, h1, o1);
            split2(-v.x, -v.y, h2, o2);
            split2(-v.z, -v.w, h3, o3);
            bh[grp][s] = make_uint4(h0, h1, h2, h3);
            bl[grp][s] = make_uint4(o0, o1, o2, o3);
        }
    }
    // c2 -> LDS (4 KB at 32768)
    *(float4*)(smem + 32768 + tid * 16) =
        *(const float4*)((const char*)c2 + tid * 16);

    // staging: wave w copies bytes [w*4096, +4096) of each 16 KB k-tile
    const int w4096 = w << 12;
    const char* gsrc0 = (const char*)chilo + w4096 + ((tid & 63) << 4);
#pragma unroll
    for (int i = 0; i < 4; ++i) // tile 0 -> buf 0
        __builtin_amdgcn_global_load_lds((gas_uint)(gsrc0 + i * 1024),
                                         (las_uint)(smem + w4096 + i * 1024),
                                         16, 0, 0);
#pragma unroll
    for (int i = 0; i < 4; ++i) // tile 1 -> buf 1
        __builtin_amdgcn_global_load_lds((gas_uint)(gsrc0 + 16384 + i * 1024),
                                         (las_uint)(smem + 16384 + w4096 + i * 1024),
                                         16, 0, 0);
    __syncthreads(); // one full drain in the prologue only

    float m1[4] = {3.4e38f, 3.4e38f, 3.4e38f, 3.4e38f};
    float m2[4] = {3.4e38f, 3.4e38f, 3.4e38f, 3.4e38f};
    int i1[4] = {0, 0, 0, 0};
    const float* c2l = (const float*)(smem + 32768);

#pragma unroll 1
    for (int t = 0; t < 32; ++t) {
        const int buf = t & 1;
        // counted wait: my 4 loads for tile t retired; t+1's stay in flight
        if (t < 31)
            asm volatile("s_waitcnt vmcnt(4)" ::: "memory");
        else
            asm volatile("s_waitcnt vmcnt(0)" ::: "memory");
        __builtin_amdgcn_s_barrier(); // all waves certified their tile-t loads
        __builtin_amdgcn_sched_barrier(0);

        const int k0 = t * 32;
        // acc[ks][grp]: D[k = k0+ks*16+l4*4+r][row = rowbase+grp*16+l15]
        f32x4 acc[2][4];
#pragma unroll
        for (int ks = 0; ks < 2; ++ks) {
            float4 cq = *(const float4*)(c2l + k0 + ks * 16 + l4 * 4);
#pragma unroll
            for (int grp = 0; grp < 4; ++grp) {
                acc[ks][grp][0] = cq.x;
                acc[ks][grp][1] = cq.y;
                acc[ks][grp][2] = cq.z;
                acc[ks][grp][3] = cq.w;
            }
        }

        const char* lhs = smem + buf * 16384;
        __builtin_amdgcn_s_setprio(1);
#pragma unroll
        for (int s = 0; s < 4; ++s) {
            short8 ahi[2], alo[2];
#pragma unroll
            for (int ks = 0; ks < 2; ++ks) {
                const int m = ks * 16 + l15;
                const int g = l4 + 4 * s;
                const int sw = m * 256 + ((g ^ (m & 15)) << 4);
                ahi[ks] = *(const short8*)(lhs + sw);
                alo[ks] = *(const short8*)(lhs + 8192 + sw);
            }
#pragma unroll
            for (int ks = 0; ks < 2; ++ks) {
#pragma unroll
                for (int grp = 0; grp < 4; ++grp) {
                    acc[ks][grp] = __builtin_amdgcn_mfma_f32_16x16x32_bf16(
                        ahi[ks], as_s8(bh[grp][s]), acc[ks][grp], 0, 0, 0);
                    acc[ks][grp] = __builtin_amdgcn_mfma_f32_16x16x32_bf16(
                        ahi[ks], as_s8(bl[grp][s]), acc[ks][grp], 0, 0, 0);
                    acc[ks][grp] = __builtin_amdgcn_mfma_f32_16x16x32_bf16(
                        alo[ks], as_s8(bh[grp][s]), acc[ks][grp], 0, 0, 0);
                }
            }
        }
        __builtin_amdgcn_s_setprio(0);
        __builtin_amdgcn_sched_barrier(0);

        // insert 8 k-values per row-state, ascending k (first-occ tie-break)
#pragma unroll
        for (int ks = 0; ks < 2; ++ks) {
#pragma unroll
            for (int r = 0; r < 4; ++r) {
                const int kk = k0 + ks * 16 + l4 * 4 + r;
#pragma unroll
                for (int grp = 0; grp < 4; ++grp) {
                    float v = acc[ks][grp][r];
                    bool lt = v < m1[grp];
                    m2[grp] = fminf(m2[grp], fmaxf(v, m1[grp]));
                    m1[grp] = fminf(m1[grp], v);
                    i1[grp] = lt ? kk : i1[grp];
                }
            }
        }

        __builtin_amdgcn_s_barrier(); // all waves done reading buf[t&1]
        __builtin_amdgcn_sched_barrier(0);
        if (t < 30) { // issue tile t+2 into the buffer just freed
            const char* gs = gsrc0 + (size_t)(t + 2) * 16384;
            char* ls = smem + buf * 16384 + w4096;
#pragma unroll
            for (int i = 0; i < 4; ++i)
                __builtin_amdgcn_global_load_lds((gas_uint)(gs + i * 1024),
                                                 (las_uint)(ls + i * 1024),
                                                 16, 0, 0);
        }
    }

    // merge k-partitions: lanes l, l^16, l^32, l^48 hold same rows (l15)
#pragma unroll
    for (int off = 16; off <= 32; off <<= 1) {
#pragma unroll
        for (int grp = 0; grp < 4; ++grp) {
            float om = __shfl_xor(m1[grp], off);
            int oi = __shfl_xor(i1[grp], off);
            float o2 = __shfl_xor(m2[grp], off);
            m2[grp] = fminf(fminf(m2[grp], o2), fmaxf(m1[grp], om));
            bool take = (om < m1[grp]) || (om == m1[grp] && oi < i1[grp]);
            m1[grp] = fminf(m1[grp], om);
            i1[grp] = take ? oi : i1[grp];
        }
    }

    // lanes 0..15 own rows rowbase + grp*16 + l
    bool flg[4];
    unsigned long long bm[4];
    int total = 0;
#pragma unroll
    for (int grp = 0; grp < 4; ++grp) {
        flg[grp] = (l < 16) && ((m2[grp] - m1[grp]) <= EPS2);
        bm[grp] = __ballot(flg[grp]);
        total += __popcll(bm[grp]);
    }
    int pos = 0;
    if (l == 0 && total) pos = atomicAdd(counter, total);
    pos = __shfl(pos, 0);
    if (l < 16) {
        int run = pos;
#pragma unroll
        for (int grp = 0; grp < 4; ++grp) {
            out[rowbase + grp * 16 + l] = i1[grp];
            if (flg[grp])
                list[run + __popcll(bm[grp] & ((1ull << l) - 1ull))] =
                    rowbase + grp * 16 + l;
            run += __popcll(bm[grp]);
        }
    }
}

// ---- pass B: exact fp32 recompute, 4 rows/wave-task, coalesced coordsT ----
__global__ __launch_bounds__(256) void centroid_exact_kernel(
    const float* __restrict__ latent, const float* __restrict__ coordsT,
    const float* __restrict__ c2, const int* __restrict__ cnt_list,
    int* __restrict__ out) {
    const int count = cnt_list[0];
    const int* list = cnt_list + 16;
    const int lane = threadIdx.x & 63;
    const int gw = (blockIdx.x * 256 + threadIdx.x) >> 6;
    const int nwaves = gridDim.x * 4;
    // lane owns k = c*64 + lane, c = 0..15 (coalesced coordsT reads)

    for (int task = gw; task * 4 < count; task += nwaves) {
        const int base = task * 4;
        const int nr = min(4, count - base);
        const float* xp[4];
        int rows[4];
#pragma unroll
        for (int j = 0; j < 4; ++j) {
            int idx = base + (j < nr ? j : nr - 1);
            rows[j] = __builtin_amdgcn_readfirstlane(list[idx]);
            xp[j] = latent + (size_t)rows[j] * D;
        }

        float acc[16][4];
#pragma unroll
        for (int c = 0; c < 16; ++c) {
            float cc = c2[c * 64 + lane];
#pragma unroll
            for (int j = 0; j < 4; ++j) acc[c][j] = cc;
        }

#pragma unroll 1
        for (int d4 = 0; d4 < D / 4; ++d4) {
            float4 xq[4];
#pragma unroll
            for (int j = 0; j < 4; ++j)
                xq[j] = *(const float4*)(xp[j] + 4 * d4);
            float ct[4][16];
#pragma unroll
            for (int dd = 0; dd < 4; ++dd)
#pragma unroll
                for (int c = 0; c < 16; ++c)
                    ct[dd][c] = coordsT[(size_t)(4 * d4 + dd) * K + c * 64 + lane];
#pragma unroll
            for (int dd = 0; dd < 4; ++dd) {
#pragma unroll
                for (int c = 0; c < 16; ++c) {
#pragma unroll
                    for (int j = 0; j < 4; ++j) {
                        float xv = (dd == 0) ? xq[j].x
                                 : (dd == 1) ? xq[j].y
                                 : (dd == 2) ? xq[j].z : xq[j].w;
                        acc[c][j] = fmaf(-xv, ct[dd][c], acc[c][j]);
                    }
                }
            }
        }

#pragma unroll
        for (int j = 0; j < 4; ++j) {
            float m1 = acc[0][j];
            int i1 = lane;
#pragma unroll
            for (int c = 1; c < 16; ++c) {
                const int kk = c * 64 + lane;
                if (acc[c][j] < m1) { m1 = acc[c][j]; i1 = kk; }
            }
#pragma unroll
            for (int off = 1; off < 64; off <<= 1) {
                float om = __shfl_xor(m1, off);
                int oi = __shfl_xor(i1, off);
                if (om < m1 || (om == m1 && oi < i1)) { m1 = om; i1 = oi; }
            }
            if (lane == 0 && j < nr) out[rows[j]] = i1;
        }
    }
}

extern "C" void kernel_launch(void* const* d_in, const int* in_sizes, int n_in,
                              void* d_out, int out_size, void* d_ws, size_t ws_size,
                              hipStream_t stream) {
    const float* latent = (const float*)d_in[0];
    const float* coords = (const float*)d_in[1];
    int* out = (int*)d_out;

    char* ws = (char*)d_ws;
    size_t off = 0;
    float* c2 = (float*)(ws + off); off += 4096;
    uint* chilo = (uint*)(ws + off); off += 524288;     // pre-swizzled hi/lo
    float* coordsT = (float*)(ws + off); off += 524288;
    int* cnt_list = (int*)(ws + off); off += 64 + 524288;
    int* counter = cnt_list;
    int* list = cnt_list + 16;

    prep_kernel<<<K / 4, 256, 0, stream>>>(coords, c2, chilo, counter);
    {
        dim3 g(K / 64, D / 64);
        transpose_kernel<<<g, 256, 0, stream>>>(coords, coordsT);
    }
    // 256 rows/block, full K per block: 512 blocks, 2 blocks/CU
    centroid_mfma_kernel<<<N / 256, 256, 0, stream>>>(latent, chilo, c2, out,
                                                      counter, list);
    centroid_exact_kernel<<<2048, 256, 0, stream>>>(latent, coordsT, c2,
                                                    cnt_list, out);
}